// Round 5
// baseline (208.387 us; speedup 1.0000x reference)
//
#include <hip/hip_runtime.h>
#include <hip/hip_bf16.h>

#define NUM_B 8
#define SEQ 1024
#define DIM 768
#define NH 12
#define DH 64

typedef __attribute__((ext_vector_type(8))) short bf16x8;
typedef __attribute__((ext_vector_type(4))) float floatx4;
typedef __attribute__((ext_vector_type(4))) unsigned short ushortx4;
typedef __attribute__((ext_vector_type(8))) unsigned short ushortx8;

__device__ __forceinline__ unsigned short f2bf(float f) {
  unsigned u = __float_as_uint(f);
  u += 0x7FFFu + ((u >> 16) & 1u);   // round-to-nearest-even
  return (unsigned short)(u >> 16);
}

// async global->LDS, 16B per lane; LDS dest = wave-uniform base + lane*16
#define GLOAD16(g, l) __builtin_amdgcn_global_load_lds( \
    (const __attribute__((address_space(1))) unsigned int*)(g), \
    (__attribute__((address_space(3))) unsigned int*)(l), 16, 0, 0)

// ---------------- one-shot fp32 -> bf16 conversion (x, Wk, Wo) -------------
__global__ __launch_bounds__(256) void convert_kernel(
    const float* __restrict__ x, const float* __restrict__ Wk,
    const float* __restrict__ Wo, unsigned short* __restrict__ xb,
    unsigned short* __restrict__ Wkb, unsigned short* __restrict__ Wob)
{
  const int NX4 = (8192 * 768) / 4;
  const int NW4 = (768 * 768) / 4;
  int i = blockIdx.x * 256 + threadIdx.x;
  const float* s; unsigned short* d; int off;
  if (i < NX4)            { s = x;  d = xb;  off = i; }
  else if (i < NX4 + NW4) { s = Wk; d = Wkb; off = i - NX4; }
  else                    { s = Wo; d = Wob; off = i - NX4 - NW4; }
  float4 v = ((const float4*)s)[off];
  ushortx4 h;
  h.x = f2bf(v.x); h.y = f2bf(v.y); h.z = f2bf(v.z); h.w = f2bf(v.w);
  ((ushortx4*)d)[off] = h;
}

// ---------------- K projection: Kbh[b,h,l,dh] = bf16(x @ Wk^T + bk) --------
// 128x128 tile, BK=64, m97 2-barrier structure, XOR-swizzled LDS tiles.
__global__ __launch_bounds__(256) void proj_k_kernel(
    const unsigned short* __restrict__ xb, const unsigned short* __restrict__ Wkb,
    const float* __restrict__ bk, unsigned short* __restrict__ Kbh)
{
  __shared__ __align__(16) unsigned short smem[16384];   // 32 KB
  unsigned short* As = smem;          // [128 rows][8 chunks, XOR-swizzled]
  unsigned short* Bs = smem + 8192;

  const int tid = threadIdx.x;
  const int lane = tid & 63;
  const int w = tid >> 6;
  const int wr = w >> 1, wc = w & 1;
  const int quad = lane >> 4, r16 = lane & 15;
  const int rs = r16 & 7;
  const int m0 = blockIdx.x * 128, n0 = blockIdx.y * 128;
  const int wbase = (tid & ~63);

  floatx4 acc[4][4] = {};

  for (int kt = 0; kt < DIM; kt += 64) {
    __syncthreads();
#pragma unroll
    for (int i = 0; i < 4; ++i) {      // A: 1024 chunks; slot(row,p) <- g=p^(row&7)
      int c = tid + i * 256;
      int row = c >> 3, g = (c & 7) ^ (row & 7);
      GLOAD16(xb + (size_t)(m0 + row) * DIM + kt + g * 8,
              As + (size_t)(wbase + i * 256) * 8);
    }
#pragma unroll
    for (int i = 0; i < 4; ++i) {
      int c = tid + i * 256;
      int row = c >> 3, g = (c & 7) ^ (row & 7);
      GLOAD16(Wkb + (size_t)(n0 + row) * DIM + kt + g * 8,
              Bs + (size_t)(wbase + i * 256) * 8);
    }
    __syncthreads();                   // drains vmcnt(0)

    bf16x8 af[4][2], bfm[4][2];
#pragma unroll
    for (int mi = 0; mi < 4; ++mi)
#pragma unroll
      for (int kc = 0; kc < 2; ++kc)
        af[mi][kc] = *(const bf16x8*)&As[(wr * 64 + mi * 16 + r16) * 64 + ((kc * 4 + quad) ^ rs) * 8];
#pragma unroll
    for (int ni = 0; ni < 4; ++ni)
#pragma unroll
      for (int kc = 0; kc < 2; ++kc)
        bfm[ni][kc] = *(const bf16x8*)&Bs[(wc * 64 + ni * 16 + r16) * 64 + ((kc * 4 + quad) ^ rs) * 8];
#pragma unroll
    for (int mi = 0; mi < 4; ++mi)
#pragma unroll
      for (int ni = 0; ni < 4; ++ni) {
        acc[mi][ni] = __builtin_amdgcn_mfma_f32_16x16x32_bf16(af[mi][0], bfm[ni][0], acc[mi][ni], 0, 0, 0);
        acc[mi][ni] = __builtin_amdgcn_mfma_f32_16x16x32_bf16(af[mi][1], bfm[ni][1], acc[mi][ni], 0, 0, 0);
      }
  }

#pragma unroll
  for (int mi = 0; mi < 4; ++mi)
#pragma unroll
    for (int ni = 0; ni < 4; ++ni) {
      int col = n0 + wc * 64 + ni * 16 + r16;   // j = h*64+dh
      float bias = bk[col];
      int hh = col >> 6, dd = col & 63;
#pragma unroll
      for (int r = 0; r < 4; ++r) {
        int row = m0 + wr * 64 + mi * 16 + quad * 4 + r;
        int bb = row >> 10, ll = row & 1023;
        Kbh[((size_t)(bb * NH + hh) * SEQ + ll) * DH + dd] = f2bf(acc[mi][ni][r] + bias);
      }
    }
}

// ---------------- transpose: Kbh[bh][l][dh] -> KbhT[bh][dh][l] -------------
// 64x64 tile; swizzled LDS (global source permuted); conflict-free reads.
__global__ __launch_bounds__(256) void transpose_kernel(
    const unsigned short* __restrict__ Kbh, unsigned short* __restrict__ KbhT)
{
  __shared__ __align__(16) unsigned short Ts[4096];  // [64 l][8 chunks swizzled]
  const int tid = threadIdx.x;
  const int bh = blockIdx.x, lt = blockIdx.y;
  const int l0 = lt * 64;
  const unsigned short* src = Kbh + (size_t)bh * SEQ * DH;
  unsigned short* dst = KbhT + (size_t)bh * DH * SEQ;
  const int wbase = (tid & ~63);

#pragma unroll
  for (int i = 0; i < 2; ++i) {
    int c = tid + i * 256;
    int row = c >> 3, g = (c & 7) ^ (row & 7);
    GLOAD16(src + (size_t)(l0 + row) * DH + g * 8,
            Ts + (size_t)(wbase + i * 256) * 8);
  }
  __syncthreads();
#pragma unroll
  for (int i = 0; i < 2; ++i) {
    int c = tid + i * 256;
    int d = c >> 3, ch = c & 7;
    ushortx8 v;
#pragma unroll
    for (int j = 0; j < 8; ++j)
      v[j] = Ts[(ch * 8 + j) * 64 + (((d >> 3) ^ j) * 8) + (d & 7)];
    *(ushortx8*)&dst[(size_t)d * SEQ + l0 + ch * 8] = v;
  }
}

// ---------------- fused attention ------------------------------------------
// grid (bh=96, qt=8): same-bh blocks share an XCD (id mod 8 = bh mod 8).
// 128 q-rows/block, dbuf 64-key tiles, swizzled Ks/KTs, stride-68 Ps.
__global__ __launch_bounds__(256) void attn_kernel(
    const unsigned short* __restrict__ Kbh, const unsigned short* __restrict__ KbhT,
    const int* __restrict__ mask, unsigned short* __restrict__ wV)
{
  __shared__ __align__(16) unsigned short smem[25088];   // 49 KB
  // Ks(buf)=smem+buf*4096 [64key][8ch swz]; KTs(buf)=smem+8192+buf*4096;
  // Ps=smem+16384 [128][68]
  unsigned short* Ps = smem + 16384;

  const int tid = threadIdx.x;
  const int lane = tid & 63;
  const int w = tid >> 6;
  const int quad = lane >> 4, r16 = lane & 15;
  const int rs = r16 & 7;
  const int bh = blockIdx.x, qt = blockIdx.y;
  const int b = bh / NH, h = bh % NH;
  const unsigned short* Kb  = Kbh  + (size_t)bh * SEQ * DH;
  const unsigned short* KbT = KbhT + (size_t)bh * DH * SEQ;
  const int q0 = qt * 128;
  const int wbase = (tid & ~63);
  const float SC2 = 0.05205809663084291f;  // 1/sqrt(768) * log2(e)

  bf16x8 aq[2][2];
#pragma unroll
  for (int mi = 0; mi < 2; ++mi)
#pragma unroll
    for (int kc = 0; kc < 2; ++kc)
      aq[mi][kc] = *(const bf16x8*)(Kb + (size_t)(q0 + w * 32 + mi * 16 + r16) * DH + kc * 32 + quad * 8);

  bool mok[2][4];
#pragma unroll
  for (int mi = 0; mi < 2; ++mi)
#pragma unroll
    for (int r = 0; r < 4; ++r)
      mok[mi][r] = (mask[b * SEQ + q0 + w * 32 + mi * 16 + quad * 4 + r] != 0);

  floatx4 accO[2][4] = {};
  float psum[2][4] = {};

  auto stage = [&](int kt, int buf) {
    unsigned short* Ks  = smem + buf * 4096;
    unsigned short* KTs = smem + 8192 + buf * 4096;
#pragma unroll
    for (int i = 0; i < 2; ++i) {
      int c = tid + i * 256;
      int row = c >> 3, g = (c & 7) ^ (row & 7);
      GLOAD16(Kb + (size_t)(kt + row) * DH + g * 8,
              Ks + (size_t)(wbase + i * 256) * 8);
    }
#pragma unroll
    for (int i = 0; i < 2; ++i) {
      int c = tid + i * 256;
      int row = c >> 3, g = (c & 7) ^ (row & 7);
      GLOAD16(KbT + (size_t)row * SEQ + kt + g * 8,
              KTs + (size_t)(wbase + i * 256) * 8);
    }
  };

  stage(0, 0);
  int buf = 0;
  for (int it = 0; it < SEQ / 64; ++it) {
    __syncthreads();
    if (it + 1 < SEQ / 64) stage((it + 1) * 64, buf ^ 1);
    const unsigned short* Ks  = smem + buf * 4096;
    const unsigned short* KTs = smem + 8192 + buf * 4096;

    // S = Q K^T (contraction over dh)
    floatx4 S[2][4] = {};
#pragma unroll
    for (int ni = 0; ni < 4; ++ni) {
      int rb = (ni * 16 + r16) * 64;
      bf16x8 b0 = *(const bf16x8*)&Ks[rb + ((quad) ^ rs) * 8];
      bf16x8 b1 = *(const bf16x8*)&Ks[rb + ((4 + quad) ^ rs) * 8];
#pragma unroll
      for (int mi = 0; mi < 2; ++mi) {
        S[mi][ni] = __builtin_amdgcn_mfma_f32_16x16x32_bf16(aq[mi][0], b0, S[mi][ni], 0, 0, 0);
        S[mi][ni] = __builtin_amdgcn_mfma_f32_16x16x32_bf16(aq[mi][1], b1, S[mi][ni], 0, 0, 0);
      }
    }

    // P = exp2(S*c); masked row -> 1 (uniform softmax). |S*c| small: no max.
#pragma unroll
    for (int mi = 0; mi < 2; ++mi)
#pragma unroll
      for (int r = 0; r < 4; ++r) {
        int prow = (w * 32 + mi * 16 + quad * 4 + r) * 68;
#pragma unroll
        for (int ni = 0; ni < 4; ++ni) {
          float p = mok[mi][r] ? exp2f(S[mi][ni][r] * SC2) : 1.0f;
          psum[mi][r] += p;
          Ps[prow + ni * 16 + r16] = f2bf(p);
        }
      }

    // O += P V (same-wave LDS RAW on Ps; V^T tile from KTs)
    bf16x8 ap[2][2];
#pragma unroll
    for (int mi = 0; mi < 2; ++mi)
#pragma unroll
      for (int kc = 0; kc < 2; ++kc)
        ap[mi][kc] = *(const bf16x8*)&Ps[(w * 32 + mi * 16 + r16) * 68 + kc * 32 + quad * 8];
#pragma unroll
    for (int ni = 0; ni < 4; ++ni) {
      int rb = (ni * 16 + r16) * 64;
      bf16x8 v0 = *(const bf16x8*)&KTs[rb + ((quad) ^ rs) * 8];
      bf16x8 v1 = *(const bf16x8*)&KTs[rb + ((4 + quad) ^ rs) * 8];
#pragma unroll
      for (int mi = 0; mi < 2; ++mi) {
        accO[mi][ni] = __builtin_amdgcn_mfma_f32_16x16x32_bf16(ap[mi][0], v0, accO[mi][ni], 0, 0, 0);
        accO[mi][ni] = __builtin_amdgcn_mfma_f32_16x16x32_bf16(ap[mi][1], v1, accO[mi][ni], 0, 0, 0);
      }
    }
    buf ^= 1;
  }

  float rinv[2][4];
#pragma unroll
  for (int mi = 0; mi < 2; ++mi)
#pragma unroll
    for (int r = 0; r < 4; ++r) {
      float s = psum[mi][r];
      s += __shfl_xor(s, 1);
      s += __shfl_xor(s, 2);
      s += __shfl_xor(s, 4);
      s += __shfl_xor(s, 8);
      rinv[mi][r] = 1.0f / s;
    }
#pragma unroll
  for (int mi = 0; mi < 2; ++mi)
#pragma unroll
    for (int ni = 0; ni < 4; ++ni)
#pragma unroll
      for (int r = 0; r < 4; ++r) {
        int l = q0 + w * 32 + mi * 16 + quad * 4 + r;
        int col = h * DH + ni * 16 + r16;
        wV[(size_t)(b * SEQ + l) * DIM + col] = f2bf(accO[mi][ni][r] * rinv[mi][r]);
      }
}

// ---------------- output projection: out = wV @ Wo^T + bo (fp32) -----------
__global__ __launch_bounds__(256) void proj_o_kernel(
    const unsigned short* __restrict__ wVb, const unsigned short* __restrict__ Wob,
    const float* __restrict__ bo, float* __restrict__ out)
{
  __shared__ __align__(16) unsigned short smem[16384];
  unsigned short* As = smem;
  unsigned short* Bs = smem + 8192;

  const int tid = threadIdx.x;
  const int lane = tid & 63;
  const int w = tid >> 6;
  const int wr = w >> 1, wc = w & 1;
  const int quad = lane >> 4, r16 = lane & 15;
  const int rs = r16 & 7;
  const int m0 = blockIdx.x * 128, n0 = blockIdx.y * 128;
  const int wbase = (tid & ~63);

  floatx4 acc[4][4] = {};

  for (int kt = 0; kt < DIM; kt += 64) {
    __syncthreads();
#pragma unroll
    for (int i = 0; i < 4; ++i) {
      int c = tid + i * 256;
      int row = c >> 3, g = (c & 7) ^ (row & 7);
      GLOAD16(wVb + (size_t)(m0 + row) * DIM + kt + g * 8,
              As + (size_t)(wbase + i * 256) * 8);
    }
#pragma unroll
    for (int i = 0; i < 4; ++i) {
      int c = tid + i * 256;
      int row = c >> 3, g = (c & 7) ^ (row & 7);
      GLOAD16(Wob + (size_t)(n0 + row) * DIM + kt + g * 8,
              Bs + (size_t)(wbase + i * 256) * 8);
    }
    __syncthreads();

    bf16x8 af[4][2], bfm[4][2];
#pragma unroll
    for (int mi = 0; mi < 4; ++mi)
#pragma unroll
      for (int kc = 0; kc < 2; ++kc)
        af[mi][kc] = *(const bf16x8*)&As[(wr * 64 + mi * 16 + r16) * 64 + ((kc * 4 + quad) ^ rs) * 8];
#pragma unroll
    for (int ni = 0; ni < 4; ++ni)
#pragma unroll
      for (int kc = 0; kc < 2; ++kc)
        bfm[ni][kc] = *(const bf16x8*)&Bs[(wc * 64 + ni * 16 + r16) * 64 + ((kc * 4 + quad) ^ rs) * 8];
#pragma unroll
    for (int mi = 0; mi < 4; ++mi)
#pragma unroll
      for (int ni = 0; ni < 4; ++ni) {
        acc[mi][ni] = __builtin_amdgcn_mfma_f32_16x16x32_bf16(af[mi][0], bfm[ni][0], acc[mi][ni], 0, 0, 0);
        acc[mi][ni] = __builtin_amdgcn_mfma_f32_16x16x32_bf16(af[mi][1], bfm[ni][1], acc[mi][ni], 0, 0, 0);
      }
  }

#pragma unroll
  for (int mi = 0; mi < 4; ++mi)
#pragma unroll
    for (int ni = 0; ni < 4; ++ni) {
      int col = n0 + wc * 64 + ni * 16 + r16;
      float bias = bo[col];
#pragma unroll
      for (int r = 0; r < 4; ++r) {
        int row = m0 + wr * 64 + mi * 16 + quad * 4 + r;
        out[(size_t)row * DIM + col] = acc[mi][ni][r] + bias;
      }
    }
}

extern "C" void kernel_launch(void* const* d_in, const int* in_sizes, int n_in,
                              void* d_out, int out_size, void* d_ws, size_t ws_size,
                              hipStream_t stream) {
  // inputs: x, attention_mask, Wq, bq, Wk, bk, Wv, bv, Wo, bo  (Q dead; V==K)
  const float* x  = (const float*)d_in[0];
  const int* mask = (const int*)d_in[1];
  const float* Wk = (const float*)d_in[4];
  const float* bk = (const float*)d_in[5];
  const float* Wo = (const float*)d_in[8];
  const float* bo = (const float*)d_in[9];
  float* out = (float*)d_out;

  unsigned short* p = (unsigned short*)d_ws;
  unsigned short* xb   = p;  p += (size_t)8192 * 768;
  unsigned short* Wkb  = p;  p += (size_t)768 * 768;
  unsigned short* Wob  = p;  p += (size_t)768 * 768;
  unsigned short* Kbh  = p;  p += (size_t)NUM_B * NH * SEQ * DH;
  unsigned short* KbhT = p;  p += (size_t)NUM_B * NH * SEQ * DH;
  unsigned short* wVb  = p;  // [8192][768]

  convert_kernel<<<7296, 256, 0, stream>>>(x, Wk, Wo, xb, Wkb, Wob);
  proj_k_kernel<<<dim3(64, 6), 256, 0, stream>>>(xb, Wkb, bk, Kbh);
  transpose_kernel<<<dim3(NUM_B * NH, 16), 256, 0, stream>>>(Kbh, KbhT);
  attn_kernel<<<dim3(NUM_B * NH, 8), 256, 0, stream>>>(Kbh, KbhT, mask, wVb);
  proj_o_kernel<<<dim3(64, 6), 256, 0, stream>>>(wVb, Wob, bo, out);
}

// Round 6
// 190.077 us; speedup vs baseline: 1.0963x; 1.0963x over previous
//
#include <hip/hip_runtime.h>
#include <hip/hip_bf16.h>

#define NUM_B 8
#define SEQ 1024
#define DIM 768
#define NH 12
#define DH 64

typedef __attribute__((ext_vector_type(8))) short bf16x8;
typedef __attribute__((ext_vector_type(4))) float floatx4;
typedef __attribute__((ext_vector_type(4))) unsigned short ushortx4;
typedef __attribute__((ext_vector_type(8))) unsigned short ushortx8;

__device__ __forceinline__ unsigned short f2bf(float f) {
  unsigned u = __float_as_uint(f);
  u += 0x7FFFu + ((u >> 16) & 1u);   // round-to-nearest-even
  return (unsigned short)(u >> 16);
}

// async global->LDS, 16B per lane; LDS dest = wave-uniform base + lane*16
#define GLOAD16(g, l) __builtin_amdgcn_global_load_lds( \
    (const __attribute__((address_space(1))) unsigned int*)(g), \
    (__attribute__((address_space(3))) unsigned int*)(l), 16, 0, 0)

// ---------------- one-shot fp32 -> bf16 conversion (x, Wk, Wo) -------------
__global__ __launch_bounds__(256) void convert_kernel(
    const float* __restrict__ x, const float* __restrict__ Wk,
    const float* __restrict__ Wo, unsigned short* __restrict__ xb,
    unsigned short* __restrict__ Wkb, unsigned short* __restrict__ Wob)
{
  const int NX4 = (8192 * 768) / 4;
  const int NW4 = (768 * 768) / 4;
  int i = blockIdx.x * 256 + threadIdx.x;
  const float* s; unsigned short* d; int off;
  if (i < NX4)            { s = x;  d = xb;  off = i; }
  else if (i < NX4 + NW4) { s = Wk; d = Wkb; off = i - NX4; }
  else                    { s = Wo; d = Wob; off = i - NX4 - NW4; }
  float4 v = ((const float4*)s)[off];
  ushortx4 h;
  h.x = f2bf(v.x); h.y = f2bf(v.y); h.z = f2bf(v.z); h.w = f2bf(v.w);
  ((ushortx4*)d)[off] = h;
}

// ---------------- K projection: Kbh[b,h,l,dh] = bf16(x @ Wk^T + bk) --------
// 64(M) x 128(N), BK=64, dbuf swizzled global_load_lds, grid 768 (3/CU).
__global__ __launch_bounds__(256) void proj_k_kernel(
    const unsigned short* __restrict__ xb, const unsigned short* __restrict__ Wkb,
    const float* __restrict__ bk, unsigned short* __restrict__ Kbh)
{
  __shared__ __align__(16) unsigned short smem[24576];   // 48 KB (2 x 24 KB)
  // buf: As = smem + buf*12288 [64][64 swz]; Bs = As + 4096 [128][64 swz]
  const int tid = threadIdx.x;
  const int lane = tid & 63;
  const int w = tid >> 6;
  const int wr = w >> 1, wc = w & 1;
  const int quad = lane >> 4, r16 = lane & 15;
  const int rs = r16 & 7;
  const int m0 = blockIdx.x * 64, n0 = blockIdx.y * 128;
  const int wbase = (tid & ~63);

  floatx4 acc[2][4] = {};

  auto stage = [&](int kt, int buf) {
    unsigned short* As = smem + buf * 12288;
    unsigned short* Bs = As + 4096;
#pragma unroll
    for (int i = 0; i < 2; ++i) {        // A: 512 chunks, swizzled source
      int c = tid + i * 256;
      int row = c >> 3, g = (c & 7) ^ (row & 7);
      GLOAD16(xb + (size_t)(m0 + row) * DIM + kt + g * 8,
              As + (size_t)(wbase + i * 256) * 8);
    }
#pragma unroll
    for (int i = 0; i < 4; ++i) {        // B: 1024 chunks
      int c = tid + i * 256;
      int row = c >> 3, g = (c & 7) ^ (row & 7);
      GLOAD16(Wkb + (size_t)(n0 + row) * DIM + kt + g * 8,
              Bs + (size_t)(wbase + i * 256) * 8);
    }
  };

  stage(0, 0);
  int buf = 0;
  for (int it = 0; it < 12; ++it) {
    __syncthreads();                     // drains current buf's loads
    if (it + 1 < 12) stage((it + 1) * 64, buf ^ 1);
    const unsigned short* As = smem + buf * 12288;
    const unsigned short* Bs = As + 4096;
    bf16x8 af[2][2], bfm[4][2];
#pragma unroll
    for (int mi = 0; mi < 2; ++mi)
#pragma unroll
      for (int kc = 0; kc < 2; ++kc)
        af[mi][kc] = *(const bf16x8*)&As[(wr * 32 + mi * 16 + r16) * 64 + ((kc * 4 + quad) ^ rs) * 8];
#pragma unroll
    for (int ni = 0; ni < 4; ++ni)
#pragma unroll
      for (int kc = 0; kc < 2; ++kc)
        bfm[ni][kc] = *(const bf16x8*)&Bs[(wc * 64 + ni * 16 + r16) * 64 + ((kc * 4 + quad) ^ rs) * 8];
#pragma unroll
    for (int mi = 0; mi < 2; ++mi)
#pragma unroll
      for (int ni = 0; ni < 4; ++ni) {
        acc[mi][ni] = __builtin_amdgcn_mfma_f32_16x16x32_bf16(af[mi][0], bfm[ni][0], acc[mi][ni], 0, 0, 0);
        acc[mi][ni] = __builtin_amdgcn_mfma_f32_16x16x32_bf16(af[mi][1], bfm[ni][1], acc[mi][ni], 0, 0, 0);
      }
    buf ^= 1;
  }

#pragma unroll
  for (int mi = 0; mi < 2; ++mi)
#pragma unroll
    for (int ni = 0; ni < 4; ++ni) {
      int col = n0 + wc * 64 + ni * 16 + r16;   // j = h*64+dh
      float bias = bk[col];
      int hh = col >> 6, dd = col & 63;
#pragma unroll
      for (int r = 0; r < 4; ++r) {
        int row = m0 + wr * 32 + mi * 16 + quad * 4 + r;
        int bb = row >> 10, ll = row & 1023;
        Kbh[((size_t)(bb * NH + hh) * SEQ + ll) * DH + dd] = f2bf(acc[mi][ni][r] + bias);
      }
    }
}

// ---------------- transpose: Kbh[bh][l][dh] -> KbhT[bh][dh][l] -------------
__global__ __launch_bounds__(256) void transpose_kernel(
    const unsigned short* __restrict__ Kbh, unsigned short* __restrict__ KbhT)
{
  __shared__ __align__(16) unsigned short Ts[4096];  // [64 l][8 chunks swizzled]
  const int tid = threadIdx.x;
  const int bh = blockIdx.x, lt = blockIdx.y;
  const int l0 = lt * 64;
  const unsigned short* src = Kbh + (size_t)bh * SEQ * DH;
  unsigned short* dst = KbhT + (size_t)bh * DH * SEQ;
  const int wbase = (tid & ~63);

#pragma unroll
  for (int i = 0; i < 2; ++i) {
    int c = tid + i * 256;
    int row = c >> 3, g = (c & 7) ^ (row & 7);
    GLOAD16(src + (size_t)(l0 + row) * DH + g * 8,
            Ts + (size_t)(wbase + i * 256) * 8);
  }
  __syncthreads();
#pragma unroll
  for (int i = 0; i < 2; ++i) {
    int c = tid + i * 256;
    int d = c >> 3, ch = c & 7;
    ushortx8 v;
#pragma unroll
    for (int j = 0; j < 8; ++j)
      v[j] = Ts[(ch * 8 + j) * 64 + (((d >> 3) ^ j) * 8) + (d & 7)];
    *(ushortx8*)&dst[(size_t)d * SEQ + l0 + ch * 8] = v;
  }
}

// ---------------- fused attention ------------------------------------------
// grid (bh=96, qt=8): same-bh blocks share an XCD (id mod 8 = bh mod 8).
// 128 q-rows/block, dbuf 64-key tiles, swizzled Ks/KTs, stride-68 Ps.
__global__ __launch_bounds__(256) void attn_kernel(
    const unsigned short* __restrict__ Kbh, const unsigned short* __restrict__ KbhT,
    const int* __restrict__ mask, unsigned short* __restrict__ wV)
{
  __shared__ __align__(16) unsigned short smem[25088];   // 49 KB
  unsigned short* Ps = smem + 16384;   // [128][68]

  const int tid = threadIdx.x;
  const int lane = tid & 63;
  const int w = tid >> 6;
  const int quad = lane >> 4, r16 = lane & 15;
  const int rs = r16 & 7;
  const int bh = blockIdx.x, qt = blockIdx.y;
  const int b = bh / NH, h = bh % NH;
  const unsigned short* Kb  = Kbh  + (size_t)bh * SEQ * DH;
  const unsigned short* KbT = KbhT + (size_t)bh * DH * SEQ;
  const int q0 = qt * 128;
  const int wbase = (tid & ~63);
  const float SCALE = 0.036084391824351615f;  // 1/sqrt(768)

  bf16x8 aq[2][2];
#pragma unroll
  for (int mi = 0; mi < 2; ++mi)
#pragma unroll
    for (int kc = 0; kc < 2; ++kc)
      aq[mi][kc] = *(const bf16x8*)(Kb + (size_t)(q0 + w * 32 + mi * 16 + r16) * DH + kc * 32 + quad * 8);

  bool mok[2][4];
#pragma unroll
  for (int mi = 0; mi < 2; ++mi)
#pragma unroll
    for (int r = 0; r < 4; ++r)
      mok[mi][r] = (mask[b * SEQ + q0 + w * 32 + mi * 16 + quad * 4 + r] != 0);

  floatx4 accO[2][4] = {};
  float psum[2][4] = {};

  auto stage = [&](int kt, int buf) {
    unsigned short* Ks  = smem + buf * 4096;
    unsigned short* KTs = smem + 8192 + buf * 4096;
#pragma unroll
    for (int i = 0; i < 2; ++i) {
      int c = tid + i * 256;
      int row = c >> 3, g = (c & 7) ^ (row & 7);
      GLOAD16(Kb + (size_t)(kt + row) * DH + g * 8,
              Ks + (size_t)(wbase + i * 256) * 8);
    }
#pragma unroll
    for (int i = 0; i < 2; ++i) {
      int c = tid + i * 256;
      int row = c >> 3, g = (c & 7) ^ (row & 7);
      GLOAD16(KbT + (size_t)row * SEQ + kt + g * 8,
              KTs + (size_t)(wbase + i * 256) * 8);
    }
  };

  stage(0, 0);
  int buf = 0;
  for (int it = 0; it < SEQ / 64; ++it) {
    __syncthreads();
    if (it + 1 < SEQ / 64) stage((it + 1) * 64, buf ^ 1);
    const unsigned short* Ks  = smem + buf * 4096;
    const unsigned short* KTs = smem + 8192 + buf * 4096;

    // S = Q K^T (contraction over dh)
    floatx4 S[2][4] = {};
#pragma unroll
    for (int ni = 0; ni < 4; ++ni) {
      int rb = (ni * 16 + r16) * 64;
      bf16x8 b0 = *(const bf16x8*)&Ks[rb + ((quad) ^ rs) * 8];
      bf16x8 b1 = *(const bf16x8*)&Ks[rb + ((4 + quad) ^ rs) * 8];
#pragma unroll
      for (int mi = 0; mi < 2; ++mi) {
        S[mi][ni] = __builtin_amdgcn_mfma_f32_16x16x32_bf16(aq[mi][0], b0, S[mi][ni], 0, 0, 0);
        S[mi][ni] = __builtin_amdgcn_mfma_f32_16x16x32_bf16(aq[mi][1], b1, S[mi][ni], 0, 0, 0);
      }
    }

    // P = exp(S*scale) via native v_exp; masked row -> 1 (uniform softmax).
#pragma unroll
    for (int mi = 0; mi < 2; ++mi)
#pragma unroll
      for (int r = 0; r < 4; ++r) {
        int prow = (w * 32 + mi * 16 + quad * 4 + r) * 68;
#pragma unroll
        for (int ni = 0; ni < 4; ++ni) {
          float p = mok[mi][r] ? __expf(S[mi][ni][r] * SCALE) : 1.0f;
          psum[mi][r] += p;
          Ps[prow + ni * 16 + r16] = f2bf(p);
        }
      }

    // O += P V (same-wave LDS RAW on Ps; V^T tile from KTs)
    bf16x8 ap[2][2];
#pragma unroll
    for (int mi = 0; mi < 2; ++mi)
#pragma unroll
      for (int kc = 0; kc < 2; ++kc)
        ap[mi][kc] = *(const bf16x8*)&Ps[(w * 32 + mi * 16 + r16) * 68 + kc * 32 + quad * 8];
#pragma unroll
    for (int ni = 0; ni < 4; ++ni) {
      int rb = (ni * 16 + r16) * 64;
      bf16x8 v0 = *(const bf16x8*)&KTs[rb + ((quad) ^ rs) * 8];
      bf16x8 v1 = *(const bf16x8*)&KTs[rb + ((4 + quad) ^ rs) * 8];
#pragma unroll
      for (int mi = 0; mi < 2; ++mi) {
        accO[mi][ni] = __builtin_amdgcn_mfma_f32_16x16x32_bf16(ap[mi][0], v0, accO[mi][ni], 0, 0, 0);
        accO[mi][ni] = __builtin_amdgcn_mfma_f32_16x16x32_bf16(ap[mi][1], v1, accO[mi][ni], 0, 0, 0);
      }
    }
    buf ^= 1;
  }

  float rinv[2][4];
#pragma unroll
  for (int mi = 0; mi < 2; ++mi)
#pragma unroll
    for (int r = 0; r < 4; ++r) {
      float s = psum[mi][r];
      s += __shfl_xor(s, 1);
      s += __shfl_xor(s, 2);
      s += __shfl_xor(s, 4);
      s += __shfl_xor(s, 8);
      rinv[mi][r] = 1.0f / s;
    }
#pragma unroll
  for (int mi = 0; mi < 2; ++mi)
#pragma unroll
    for (int ni = 0; ni < 4; ++ni)
#pragma unroll
      for (int r = 0; r < 4; ++r) {
        int l = q0 + w * 32 + mi * 16 + quad * 4 + r;
        int col = h * DH + ni * 16 + r16;
        wV[(size_t)(b * SEQ + l) * DIM + col] = f2bf(accO[mi][ni][r] * rinv[mi][r]);
      }
}

// ---------------- output projection: out = wV @ Wo^T + bo (fp32) -----------
// 64(M) x 128(N), BK=64, dbuf swizzled global_load_lds, grid 768 (3/CU).
__global__ __launch_bounds__(256) void proj_o_kernel(
    const unsigned short* __restrict__ wVb, const unsigned short* __restrict__ Wob,
    const float* __restrict__ bo, float* __restrict__ out)
{
  __shared__ __align__(16) unsigned short smem[24576];   // 48 KB
  const int tid = threadIdx.x;
  const int lane = tid & 63;
  const int w = tid >> 6;
  const int wr = w >> 1, wc = w & 1;
  const int quad = lane >> 4, r16 = lane & 15;
  const int rs = r16 & 7;
  const int m0 = blockIdx.x * 64, n0 = blockIdx.y * 128;
  const int wbase = (tid & ~63);

  floatx4 acc[2][4] = {};

  auto stage = [&](int kt, int buf) {
    unsigned short* As = smem + buf * 12288;
    unsigned short* Bs = As + 4096;
#pragma unroll
    for (int i = 0; i < 2; ++i) {
      int c = tid + i * 256;
      int row = c >> 3, g = (c & 7) ^ (row & 7);
      GLOAD16(wVb + (size_t)(m0 + row) * DIM + kt + g * 8,
              As + (size_t)(wbase + i * 256) * 8);
    }
#pragma unroll
    for (int i = 0; i < 4; ++i) {
      int c = tid + i * 256;
      int row = c >> 3, g = (c & 7) ^ (row & 7);
      GLOAD16(Wob + (size_t)(n0 + row) * DIM + kt + g * 8,
              Bs + (size_t)(wbase + i * 256) * 8);
    }
  };

  stage(0, 0);
  int buf = 0;
  for (int it = 0; it < 12; ++it) {
    __syncthreads();
    if (it + 1 < 12) stage((it + 1) * 64, buf ^ 1);
    const unsigned short* As = smem + buf * 12288;
    const unsigned short* Bs = As + 4096;
    bf16x8 af[2][2], bfm[4][2];
#pragma unroll
    for (int mi = 0; mi < 2; ++mi)
#pragma unroll
      for (int kc = 0; kc < 2; ++kc)
        af[mi][kc] = *(const bf16x8*)&As[(wr * 32 + mi * 16 + r16) * 64 + ((kc * 4 + quad) ^ rs) * 8];
#pragma unroll
    for (int ni = 0; ni < 4; ++ni)
#pragma unroll
      for (int kc = 0; kc < 2; ++kc)
        bfm[ni][kc] = *(const bf16x8*)&Bs[(wc * 64 + ni * 16 + r16) * 64 + ((kc * 4 + quad) ^ rs) * 8];
#pragma unroll
    for (int mi = 0; mi < 2; ++mi)
#pragma unroll
      for (int ni = 0; ni < 4; ++ni) {
        acc[mi][ni] = __builtin_amdgcn_mfma_f32_16x16x32_bf16(af[mi][0], bfm[ni][0], acc[mi][ni], 0, 0, 0);
        acc[mi][ni] = __builtin_amdgcn_mfma_f32_16x16x32_bf16(af[mi][1], bfm[ni][1], acc[mi][ni], 0, 0, 0);
      }
    buf ^= 1;
  }

#pragma unroll
  for (int mi = 0; mi < 2; ++mi)
#pragma unroll
    for (int ni = 0; ni < 4; ++ni) {
      int col = n0 + wc * 64 + ni * 16 + r16;
      float bias = bo[col];
#pragma unroll
      for (int r = 0; r < 4; ++r) {
        int row = m0 + wr * 32 + mi * 16 + quad * 4 + r;
        out[(size_t)row * DIM + col] = acc[mi][ni][r] + bias;
      }
    }
}

extern "C" void kernel_launch(void* const* d_in, const int* in_sizes, int n_in,
                              void* d_out, int out_size, void* d_ws, size_t ws_size,
                              hipStream_t stream) {
  // inputs: x, attention_mask, Wq, bq, Wk, bk, Wv, bv, Wo, bo  (Q dead; V==K)
  const float* x  = (const float*)d_in[0];
  const int* mask = (const int*)d_in[1];
  const float* Wk = (const float*)d_in[4];
  const float* bk = (const float*)d_in[5];
  const float* Wo = (const float*)d_in[8];
  const float* bo = (const float*)d_in[9];
  float* out = (float*)d_out;

  unsigned short* p = (unsigned short*)d_ws;
  unsigned short* xb   = p;  p += (size_t)8192 * 768;
  unsigned short* Wkb  = p;  p += (size_t)768 * 768;
  unsigned short* Wob  = p;  p += (size_t)768 * 768;
  unsigned short* Kbh  = p;  p += (size_t)NUM_B * NH * SEQ * DH;
  unsigned short* KbhT = p;  p += (size_t)NUM_B * NH * SEQ * DH;
  unsigned short* wVb  = p;  // [8192][768]

  convert_kernel<<<7296, 256, 0, stream>>>(x, Wk, Wo, xb, Wkb, Wob);
  proj_k_kernel<<<dim3(128, 6), 256, 0, stream>>>(xb, Wkb, bk, Kbh);
  transpose_kernel<<<dim3(NUM_B * NH, 16), 256, 0, stream>>>(Kbh, KbhT);
  attn_kernel<<<dim3(NUM_B * NH, 8), 256, 0, stream>>>(Kbh, KbhT, mask, wVb);
  proj_o_kernel<<<dim3(128, 6), 256, 0, stream>>>(wVb, Wob, bo, out);
}

// Round 7
// 183.306 us; speedup vs baseline: 1.1368x; 1.0369x over previous
//
#include <hip/hip_runtime.h>
#include <hip/hip_bf16.h>

#define NUM_B 8
#define SEQ 1024
#define DIM 768
#define NH 12
#define DH 64

typedef __attribute__((ext_vector_type(8))) short bf16x8;
typedef __attribute__((ext_vector_type(4))) float floatx4;
typedef __attribute__((ext_vector_type(4))) unsigned short ushortx4;
typedef __attribute__((ext_vector_type(8))) unsigned short ushortx8;

__device__ __forceinline__ unsigned short f2bf(float f) {
  unsigned u = __float_as_uint(f);
  u += 0x7FFFu + ((u >> 16) & 1u);   // round-to-nearest-even
  return (unsigned short)(u >> 16);
}

// async global->LDS, 16B per lane; LDS dest = wave-uniform base + lane*16
#define GLOAD16(g, l) __builtin_amdgcn_global_load_lds( \
    (const __attribute__((address_space(1))) unsigned int*)(g), \
    (__attribute__((address_space(3))) unsigned int*)(l), 16, 0, 0)

// ---------------- one-shot fp32 -> bf16 conversion (x, Wk, Wo) -------------
__global__ __launch_bounds__(256) void convert_kernel(
    const float* __restrict__ x, const float* __restrict__ Wk,
    const float* __restrict__ Wo, unsigned short* __restrict__ xb,
    unsigned short* __restrict__ Wkb, unsigned short* __restrict__ Wob)
{
  const int NX4 = (8192 * 768) / 4;
  const int NW4 = (768 * 768) / 4;
  int i = blockIdx.x * 256 + threadIdx.x;
  const float* s; unsigned short* d; int off;
  if (i < NX4)            { s = x;  d = xb;  off = i; }
  else if (i < NX4 + NW4) { s = Wk; d = Wkb; off = i - NX4; }
  else                    { s = Wo; d = Wob; off = i - NX4 - NW4; }
  float4 v = ((const float4*)s)[off];
  ushortx4 h;
  h.x = f2bf(v.x); h.y = f2bf(v.y); h.z = f2bf(v.z); h.w = f2bf(v.w);
  ((ushortx4*)d)[off] = h;
}

// ---------------- K projection + fused transpose ---------------------------
// 64(M) x 128(N), BK=64, dbuf swizzled global_load_lds, grid 768 (3/CU).
// Epilogue writes Kbh[b,h,l,dh] AND KbhT[b,h,dh,l] (LDS-transposed tile).
__global__ __launch_bounds__(256) void proj_k_kernel(
    const unsigned short* __restrict__ xb, const unsigned short* __restrict__ Wkb,
    const float* __restrict__ bk, unsigned short* __restrict__ Kbh,
    unsigned short* __restrict__ KbhT)
{
  __shared__ __align__(16) unsigned short smem[24576];   // 48 KB (2 x 24 KB)
  const int tid = threadIdx.x;
  const int lane = tid & 63;
  const int w = tid >> 6;
  const int wr = w >> 1, wc = w & 1;
  const int quad = lane >> 4, r16 = lane & 15;
  const int rs = r16 & 7;
  const int m0 = blockIdx.x * 64, n0 = blockIdx.y * 128;
  const int wbase = (tid & ~63);

  floatx4 acc[2][4] = {};

  auto stage = [&](int kt, int buf) {
    unsigned short* As = smem + buf * 12288;
    unsigned short* Bs = As + 4096;
#pragma unroll
    for (int i = 0; i < 2; ++i) {        // A: 512 chunks, swizzled source
      int c = tid + i * 256;
      int row = c >> 3, g = (c & 7) ^ (row & 7);
      GLOAD16(xb + (size_t)(m0 + row) * DIM + kt + g * 8,
              As + (size_t)(wbase + i * 256) * 8);
    }
#pragma unroll
    for (int i = 0; i < 4; ++i) {        // B: 1024 chunks
      int c = tid + i * 256;
      int row = c >> 3, g = (c & 7) ^ (row & 7);
      GLOAD16(Wkb + (size_t)(n0 + row) * DIM + kt + g * 8,
              Bs + (size_t)(wbase + i * 256) * 8);
    }
  };

  stage(0, 0);
  int buf = 0;
  for (int it = 0; it < 12; ++it) {
    __syncthreads();                     // drains current buf's loads
    if (it + 1 < 12) stage((it + 1) * 64, buf ^ 1);
    const unsigned short* As = smem + buf * 12288;
    const unsigned short* Bs = As + 4096;
    bf16x8 af[2][2], bfm[4][2];
#pragma unroll
    for (int mi = 0; mi < 2; ++mi)
#pragma unroll
      for (int kc = 0; kc < 2; ++kc)
        af[mi][kc] = *(const bf16x8*)&As[(wr * 32 + mi * 16 + r16) * 64 + ((kc * 4 + quad) ^ rs) * 8];
#pragma unroll
    for (int ni = 0; ni < 4; ++ni)
#pragma unroll
      for (int kc = 0; kc < 2; ++kc)
        bfm[ni][kc] = *(const bf16x8*)&Bs[(wc * 64 + ni * 16 + r16) * 64 + ((kc * 4 + quad) ^ rs) * 8];
#pragma unroll
    for (int mi = 0; mi < 2; ++mi)
#pragma unroll
      for (int ni = 0; ni < 4; ++ni) {
        acc[mi][ni] = __builtin_amdgcn_mfma_f32_16x16x32_bf16(af[mi][0], bfm[ni][0], acc[mi][ni], 0, 0, 0);
        acc[mi][ni] = __builtin_amdgcn_mfma_f32_16x16x32_bf16(af[mi][1], bfm[ni][1], acc[mi][ni], 0, 0, 0);
      }
    buf ^= 1;
  }

  __syncthreads();                       // reuse smem as Ct [128 n][72]
  unsigned short* Ct = smem;
  const int bb = m0 >> 10, l0 = m0 & 1023;
#pragma unroll
  for (int mi = 0; mi < 2; ++mi)
#pragma unroll
    for (int ni = 0; ni < 4; ++ni) {
      int col = n0 + wc * 64 + ni * 16 + r16;   // j = h*64+dh
      float bias = bk[col];
      int hh = col >> 6, dd = col & 63;
      ushortx4 pk;
#pragma unroll
      for (int r = 0; r < 4; ++r) {
        int mrow = wr * 32 + mi * 16 + quad * 4 + r;   // 0..63 in tile
        unsigned short us = f2bf(acc[mi][ni][r] + bias);
        Kbh[((size_t)(bb * NH + hh) * SEQ + l0 + mrow) * DH + dd] = us;
        pk[r] = us;
      }
      *(ushortx4*)&Ct[(wc * 64 + ni * 16 + r16) * 72 + wr * 32 + mi * 16 + quad * 4] = pk;
    }
  __syncthreads();
#pragma unroll
  for (int i = 0; i < 4; ++i) {          // KbhT: [n=128][m=64] coalesced
    int c = tid + i * 256;
    int row = c >> 3, ch = c & 7;
    ushortx8 v = *(const ushortx8*)&Ct[row * 72 + ch * 8];
    int j = n0 + row;
    int hh = j >> 6, dd = j & 63;
    *(ushortx8*)&KbhT[((size_t)(bb * NH + hh) * DH + dd) * SEQ + l0 + ch * 8] = v;
  }
}

// ---------------- fused attention ------------------------------------------
// grid (qt=8, bh=96): qt fastest -> same-bh q-tiles scatter across XCDs
// (r3 mapping; XCD-local grouping measured SLOWER despite 7x less fetch).
// 128 q-rows/block, dbuf 64-key tiles, swizzled Ks/KTs, stride-68 Ps.
__global__ __launch_bounds__(256) void attn_kernel(
    const unsigned short* __restrict__ Kbh, const unsigned short* __restrict__ KbhT,
    const int* __restrict__ mask, unsigned short* __restrict__ wV)
{
  __shared__ __align__(16) unsigned short smem[25088];   // 49 KB
  unsigned short* Ps = smem + 16384;   // [128][68]

  const int tid = threadIdx.x;
  const int lane = tid & 63;
  const int w = tid >> 6;
  const int quad = lane >> 4, r16 = lane & 15;
  const int rs = r16 & 7;
  const int qt = blockIdx.x, bh = blockIdx.y;
  const int b = bh / NH, h = bh % NH;
  const unsigned short* Kb  = Kbh  + (size_t)bh * SEQ * DH;
  const unsigned short* KbT = KbhT + (size_t)bh * DH * SEQ;
  const int q0 = qt * 128;
  const int wbase = (tid & ~63);
  const float SCALE = 0.036084391824351615f;  // 1/sqrt(768)

  bf16x8 aq[2][2];
#pragma unroll
  for (int mi = 0; mi < 2; ++mi)
#pragma unroll
    for (int kc = 0; kc < 2; ++kc)
      aq[mi][kc] = *(const bf16x8*)(Kb + (size_t)(q0 + w * 32 + mi * 16 + r16) * DH + kc * 32 + quad * 8);

  // masked row => arg = S*0 = 0 => p = exp(0) = 1 (uniform softmax), no cndmask
  float scm[2][4];
#pragma unroll
  for (int mi = 0; mi < 2; ++mi)
#pragma unroll
    for (int r = 0; r < 4; ++r)
      scm[mi][r] = (mask[b * SEQ + q0 + w * 32 + mi * 16 + quad * 4 + r] != 0) ? SCALE : 0.0f;

  floatx4 accO[2][4] = {};
  float psum[2][4] = {};

  auto stage = [&](int kt, int buf) {
    unsigned short* Ks  = smem + buf * 4096;
    unsigned short* KTs = smem + 8192 + buf * 4096;
#pragma unroll
    for (int i = 0; i < 2; ++i) {
      int c = tid + i * 256;
      int row = c >> 3, g = (c & 7) ^ (row & 7);
      GLOAD16(Kb + (size_t)(kt + row) * DH + g * 8,
              Ks + (size_t)(wbase + i * 256) * 8);
    }
#pragma unroll
    for (int i = 0; i < 2; ++i) {
      int c = tid + i * 256;
      int row = c >> 3, g = (c & 7) ^ (row & 7);
      GLOAD16(KbT + (size_t)row * SEQ + kt + g * 8,
              KTs + (size_t)(wbase + i * 256) * 8);
    }
  };

  stage(0, 0);
  int buf = 0;
  for (int it = 0; it < SEQ / 64; ++it) {
    __syncthreads();
    if (it + 1 < SEQ / 64) stage((it + 1) * 64, buf ^ 1);
    const unsigned short* Ks  = smem + buf * 4096;
    const unsigned short* KTs = smem + 8192 + buf * 4096;

    // S = Q K^T (contraction over dh)
    floatx4 S[2][4] = {};
#pragma unroll
    for (int ni = 0; ni < 4; ++ni) {
      int rb = (ni * 16 + r16) * 64;
      bf16x8 b0 = *(const bf16x8*)&Ks[rb + ((quad) ^ rs) * 8];
      bf16x8 b1 = *(const bf16x8*)&Ks[rb + ((4 + quad) ^ rs) * 8];
#pragma unroll
      for (int mi = 0; mi < 2; ++mi) {
        S[mi][ni] = __builtin_amdgcn_mfma_f32_16x16x32_bf16(aq[mi][0], b0, S[mi][ni], 0, 0, 0);
        S[mi][ni] = __builtin_amdgcn_mfma_f32_16x16x32_bf16(aq[mi][1], b1, S[mi][ni], 0, 0, 0);
      }
    }

    // P = exp(S*scm); packed bf16 cvt (1 instr / 2 elems); paired b16 stores
#pragma unroll
    for (int mi = 0; mi < 2; ++mi)
#pragma unroll
      for (int r = 0; r < 4; ++r) {
        int prow = (w * 32 + mi * 16 + quad * 4 + r) * 68 + r16;
        float sc = scm[mi][r];
#pragma unroll
        for (int ni = 0; ni < 4; ni += 2) {
          float pa = __expf(S[mi][ni][r] * sc);
          float pb = __expf(S[mi][ni + 1][r] * sc);
          psum[mi][r] += pa + pb;
          __hip_bfloat162 h2 = __float22bfloat162_rn(make_float2(pa, pb));
          unsigned u; __builtin_memcpy(&u, &h2, 4);
          Ps[prow + ni * 16] = (unsigned short)u;
          Ps[prow + (ni + 1) * 16] = (unsigned short)(u >> 16);
        }
      }

    // O += P V (same-wave LDS RAW on Ps; V^T tile from KTs)
    bf16x8 ap[2][2];
#pragma unroll
    for (int mi = 0; mi < 2; ++mi)
#pragma unroll
      for (int kc = 0; kc < 2; ++kc)
        ap[mi][kc] = *(const bf16x8*)&Ps[(w * 32 + mi * 16 + r16) * 68 + kc * 32 + quad * 8];
#pragma unroll
    for (int ni = 0; ni < 4; ++ni) {
      int rb = (ni * 16 + r16) * 64;
      bf16x8 v0 = *(const bf16x8*)&KTs[rb + ((quad) ^ rs) * 8];
      bf16x8 v1 = *(const bf16x8*)&KTs[rb + ((4 + quad) ^ rs) * 8];
#pragma unroll
      for (int mi = 0; mi < 2; ++mi) {
        accO[mi][ni] = __builtin_amdgcn_mfma_f32_16x16x32_bf16(ap[mi][0], v0, accO[mi][ni], 0, 0, 0);
        accO[mi][ni] = __builtin_amdgcn_mfma_f32_16x16x32_bf16(ap[mi][1], v1, accO[mi][ni], 0, 0, 0);
      }
    }
    buf ^= 1;
  }

  float rinv[2][4];
#pragma unroll
  for (int mi = 0; mi < 2; ++mi)
#pragma unroll
    for (int r = 0; r < 4; ++r) {
      float s = psum[mi][r];
      s += __shfl_xor(s, 1);
      s += __shfl_xor(s, 2);
      s += __shfl_xor(s, 4);
      s += __shfl_xor(s, 8);
      rinv[mi][r] = 1.0f / s;
    }
#pragma unroll
  for (int mi = 0; mi < 2; ++mi)
#pragma unroll
    for (int ni = 0; ni < 4; ++ni)
#pragma unroll
      for (int r = 0; r < 4; ++r) {
        int l = q0 + w * 32 + mi * 16 + quad * 4 + r;
        int col = h * DH + ni * 16 + r16;
        wV[(size_t)(b * SEQ + l) * DIM + col] = f2bf(accO[mi][ni][r] * rinv[mi][r]);
      }
}

// ---------------- output projection: out = wV @ Wo^T + bo (fp32) -----------
// 64(M) x 128(N), BK=64, dbuf swizzled global_load_lds, grid 768 (3/CU).
__global__ __launch_bounds__(256) void proj_o_kernel(
    const unsigned short* __restrict__ wVb, const unsigned short* __restrict__ Wob,
    const float* __restrict__ bo, float* __restrict__ out)
{
  __shared__ __align__(16) unsigned short smem[24576];   // 48 KB
  const int tid = threadIdx.x;
  const int lane = tid & 63;
  const int w = tid >> 6;
  const int wr = w >> 1, wc = w & 1;
  const int quad = lane >> 4, r16 = lane & 15;
  const int rs = r16 & 7;
  const int m0 = blockIdx.x * 64, n0 = blockIdx.y * 128;
  const int wbase = (tid & ~63);

  floatx4 acc[2][4] = {};

  auto stage = [&](int kt, int buf) {
    unsigned short* As = smem + buf * 12288;
    unsigned short* Bs = As + 4096;
#pragma unroll
    for (int i = 0; i < 2; ++i) {
      int c = tid + i * 256;
      int row = c >> 3, g = (c & 7) ^ (row & 7);
      GLOAD16(wVb + (size_t)(m0 + row) * DIM + kt + g * 8,
              As + (size_t)(wbase + i * 256) * 8);
    }
#pragma unroll
    for (int i = 0; i < 4; ++i) {
      int c = tid + i * 256;
      int row = c >> 3, g = (c & 7) ^ (row & 7);
      GLOAD16(Wob + (size_t)(n0 + row) * DIM + kt + g * 8,
              Bs + (size_t)(wbase + i * 256) * 8);
    }
  };

  stage(0, 0);
  int buf = 0;
  for (int it = 0; it < 12; ++it) {
    __syncthreads();
    if (it + 1 < 12) stage((it + 1) * 64, buf ^ 1);
    const unsigned short* As = smem + buf * 12288;
    const unsigned short* Bs = As + 4096;
    bf16x8 af[2][2], bfm[4][2];
#pragma unroll
    for (int mi = 0; mi < 2; ++mi)
#pragma unroll
      for (int kc = 0; kc < 2; ++kc)
        af[mi][kc] = *(const bf16x8*)&As[(wr * 32 + mi * 16 + r16) * 64 + ((kc * 4 + quad) ^ rs) * 8];
#pragma unroll
    for (int ni = 0; ni < 4; ++ni)
#pragma unroll
      for (int kc = 0; kc < 2; ++kc)
        bfm[ni][kc] = *(const bf16x8*)&Bs[(wc * 64 + ni * 16 + r16) * 64 + ((kc * 4 + quad) ^ rs) * 8];
#pragma unroll
    for (int mi = 0; mi < 2; ++mi)
#pragma unroll
      for (int ni = 0; ni < 4; ++ni) {
        acc[mi][ni] = __builtin_amdgcn_mfma_f32_16x16x32_bf16(af[mi][0], bfm[ni][0], acc[mi][ni], 0, 0, 0);
        acc[mi][ni] = __builtin_amdgcn_mfma_f32_16x16x32_bf16(af[mi][1], bfm[ni][1], acc[mi][ni], 0, 0, 0);
      }
    buf ^= 1;
  }

#pragma unroll
  for (int mi = 0; mi < 2; ++mi)
#pragma unroll
    for (int ni = 0; ni < 4; ++ni) {
      int col = n0 + wc * 64 + ni * 16 + r16;
      float bias = bo[col];
#pragma unroll
      for (int r = 0; r < 4; ++r) {
        int row = m0 + wr * 32 + mi * 16 + quad * 4 + r;
        out[(size_t)row * DIM + col] = acc[mi][ni][r] + bias;
      }
    }
}

extern "C" void kernel_launch(void* const* d_in, const int* in_sizes, int n_in,
                              void* d_out, int out_size, void* d_ws, size_t ws_size,
                              hipStream_t stream) {
  // inputs: x, attention_mask, Wq, bq, Wk, bk, Wv, bv, Wo, bo  (Q dead; V==K)
  const float* x  = (const float*)d_in[0];
  const int* mask = (const int*)d_in[1];
  const float* Wk = (const float*)d_in[4];
  const float* bk = (const float*)d_in[5];
  const float* Wo = (const float*)d_in[8];
  const float* bo = (const float*)d_in[9];
  float* out = (float*)d_out;

  unsigned short* p = (unsigned short*)d_ws;
  unsigned short* xb   = p;  p += (size_t)8192 * 768;
  unsigned short* Wkb  = p;  p += (size_t)768 * 768;
  unsigned short* Wob  = p;  p += (size_t)768 * 768;
  unsigned short* Kbh  = p;  p += (size_t)NUM_B * NH * SEQ * DH;
  unsigned short* KbhT = p;  p += (size_t)NUM_B * NH * SEQ * DH;
  unsigned short* wVb  = p;  // [8192][768]

  convert_kernel<<<7296, 256, 0, stream>>>(x, Wk, Wo, xb, Wkb, Wob);
  proj_k_kernel<<<dim3(128, 6), 256, 0, stream>>>(xb, Wkb, bk, Kbh, KbhT);
  attn_kernel<<<dim3(8, NUM_B * NH), 256, 0, stream>>>(Kbh, KbhT, mask, wVb);
  proj_o_kernel<<<dim3(128, 6), 256, 0, stream>>>(wVb, Wob, bo, out);
}

// Round 8
// 181.716 us; speedup vs baseline: 1.1468x; 1.0088x over previous
//
#include <hip/hip_runtime.h>
#include <hip/hip_bf16.h>

#define NUM_B 8
#define SEQ 1024
#define DIM 768
#define NH 12
#define DH 64

typedef __attribute__((ext_vector_type(8))) short bf16x8;
typedef __attribute__((ext_vector_type(4))) float floatx4;
typedef __attribute__((ext_vector_type(4))) unsigned short ushortx4;
typedef __attribute__((ext_vector_type(8))) unsigned short ushortx8;

__device__ __forceinline__ unsigned short f2bf(float f) {
  unsigned u = __float_as_uint(f);
  u += 0x7FFFu + ((u >> 16) & 1u);   // round-to-nearest-even
  return (unsigned short)(u >> 16);
}

// async global->LDS, 16B per lane; LDS dest = wave-uniform base + lane*16
#define GLOAD16(g, l) __builtin_amdgcn_global_load_lds( \
    (const __attribute__((address_space(1))) unsigned int*)(g), \
    (__attribute__((address_space(3))) unsigned int*)(l), 16, 0, 0)

// ---------------- one-shot fp32 -> bf16 conversion (x, Wk, Wo) -------------
__global__ __launch_bounds__(256) void convert_kernel(
    const float* __restrict__ x, const float* __restrict__ Wk,
    const float* __restrict__ Wo, unsigned short* __restrict__ xb,
    unsigned short* __restrict__ Wkb, unsigned short* __restrict__ Wob)
{
  const int NX4 = (8192 * 768) / 4;
  const int NW4 = (768 * 768) / 4;
  int i = blockIdx.x * 256 + threadIdx.x;
  const float* s; unsigned short* d; int off;
  if (i < NX4)            { s = x;  d = xb;  off = i; }
  else if (i < NX4 + NW4) { s = Wk; d = Wkb; off = i - NX4; }
  else                    { s = Wo; d = Wob; off = i - NX4 - NW4; }
  float4 v = ((const float4*)s)[off];
  ushortx4 h;
  h.x = f2bf(v.x); h.y = f2bf(v.y); h.z = f2bf(v.z); h.w = f2bf(v.w);
  ((ushortx4*)d)[off] = h;
}

// ---------------- K projection + fused transpose ---------------------------
// 64(M) x 128(N), BK=64, dbuf swizzled global_load_lds, grid 768 (3/CU).
__global__ __launch_bounds__(256) void proj_k_kernel(
    const unsigned short* __restrict__ xb, const unsigned short* __restrict__ Wkb,
    const float* __restrict__ bk, unsigned short* __restrict__ Kbh,
    unsigned short* __restrict__ KbhT)
{
  __shared__ __align__(16) unsigned short smem[24576];   // 48 KB (2 x 24 KB)
  const int tid = threadIdx.x;
  const int lane = tid & 63;
  const int w = tid >> 6;
  const int wr = w >> 1, wc = w & 1;
  const int quad = lane >> 4, r16 = lane & 15;
  const int rs = r16 & 7;
  const int m0 = blockIdx.x * 64, n0 = blockIdx.y * 128;
  const int wbase = (tid & ~63);

  floatx4 acc[2][4] = {};

  auto stage = [&](int kt, int buf) {
    unsigned short* As = smem + buf * 12288;
    unsigned short* Bs = As + 4096;
#pragma unroll
    for (int i = 0; i < 2; ++i) {
      int c = tid + i * 256;
      int row = c >> 3, g = (c & 7) ^ (row & 7);
      GLOAD16(xb + (size_t)(m0 + row) * DIM + kt + g * 8,
              As + (size_t)(wbase + i * 256) * 8);
    }
#pragma unroll
    for (int i = 0; i < 4; ++i) {
      int c = tid + i * 256;
      int row = c >> 3, g = (c & 7) ^ (row & 7);
      GLOAD16(Wkb + (size_t)(n0 + row) * DIM + kt + g * 8,
              Bs + (size_t)(wbase + i * 256) * 8);
    }
  };

  stage(0, 0);
  int buf = 0;
  for (int it = 0; it < 12; ++it) {
    __syncthreads();
    if (it + 1 < 12) stage((it + 1) * 64, buf ^ 1);
    const unsigned short* As = smem + buf * 12288;
    const unsigned short* Bs = As + 4096;
    bf16x8 af[2][2], bfm[4][2];
#pragma unroll
    for (int mi = 0; mi < 2; ++mi)
#pragma unroll
      for (int kc = 0; kc < 2; ++kc)
        af[mi][kc] = *(const bf16x8*)&As[(wr * 32 + mi * 16 + r16) * 64 + ((kc * 4 + quad) ^ rs) * 8];
#pragma unroll
    for (int ni = 0; ni < 4; ++ni)
#pragma unroll
      for (int kc = 0; kc < 2; ++kc)
        bfm[ni][kc] = *(const bf16x8*)&Bs[(wc * 64 + ni * 16 + r16) * 64 + ((kc * 4 + quad) ^ rs) * 8];
#pragma unroll
    for (int mi = 0; mi < 2; ++mi)
#pragma unroll
      for (int ni = 0; ni < 4; ++ni) {
        acc[mi][ni] = __builtin_amdgcn_mfma_f32_16x16x32_bf16(af[mi][0], bfm[ni][0], acc[mi][ni], 0, 0, 0);
        acc[mi][ni] = __builtin_amdgcn_mfma_f32_16x16x32_bf16(af[mi][1], bfm[ni][1], acc[mi][ni], 0, 0, 0);
      }
    buf ^= 1;
  }

  __syncthreads();                       // reuse smem as Ct [128 n][72]
  unsigned short* Ct = smem;
  const int bb = m0 >> 10, l0 = m0 & 1023;
#pragma unroll
  for (int mi = 0; mi < 2; ++mi)
#pragma unroll
    for (int ni = 0; ni < 4; ++ni) {
      int col = n0 + wc * 64 + ni * 16 + r16;   // j = h*64+dh
      float bias = bk[col];
      int hh = col >> 6, dd = col & 63;
      ushortx4 pk;
#pragma unroll
      for (int r = 0; r < 4; ++r) {
        int mrow = wr * 32 + mi * 16 + quad * 4 + r;
        unsigned short us = f2bf(acc[mi][ni][r] + bias);
        Kbh[((size_t)(bb * NH + hh) * SEQ + l0 + mrow) * DH + dd] = us;
        pk[r] = us;
      }
      *(ushortx4*)&Ct[(wc * 64 + ni * 16 + r16) * 72 + wr * 32 + mi * 16 + quad * 4] = pk;
    }
  __syncthreads();
#pragma unroll
  for (int i = 0; i < 4; ++i) {
    int c = tid + i * 256;
    int row = c >> 3, ch = c & 7;
    ushortx8 v = *(const ushortx8*)&Ct[row * 72 + ch * 8];
    int j = n0 + row;
    int hh = j >> 6, dd = j & 63;
    *(ushortx8*)&KbhT[((size_t)(bb * NH + hh) * DH + dd) * SEQ + l0 + ch * 8] = v;
  }
}

// ---------------- fused attention ------------------------------------------
// grid (qt=8, bh=96). 128 q-rows/block, 4 waves x 32 q.
// S computed TRANSPOSED (St = K*Q^T, A=K from LDS, B=Q regs): C-layout gives
// each lane 4 consecutive keys -> P written as 8 ds_write_b64 (was 32 b16).
__global__ __launch_bounds__(256) void attn_kernel(
    const unsigned short* __restrict__ Kbh, const unsigned short* __restrict__ KbhT,
    const int* __restrict__ mask, unsigned short* __restrict__ wV)
{
  __shared__ __align__(16) unsigned short smem[25344];   // 49.5 KB
  // [0,16384): Ks/KTs dbuf; [16384, 25088): Ps [128][68]; [25088,): rsum f32[128]
  unsigned short* Ps = smem + 16384;
  float* rsum = (float*)&smem[25088];

  const int tid = threadIdx.x;
  const int lane = tid & 63;
  const int w = tid >> 6;
  const int quad = lane >> 4, r16 = lane & 15;
  const int rs = r16 & 7;
  const int qt = blockIdx.x, bh = blockIdx.y;
  const int b = bh / NH, h = bh % NH;
  const unsigned short* Kb  = Kbh  + (size_t)bh * SEQ * DH;
  const unsigned short* KbT = KbhT + (size_t)bh * DH * SEQ;
  const int q0 = qt * 128;
  const int qw = w * 32;                 // wave's q-range within tile
  const int wbase = (tid & ~63);
  const float SCALE = 0.036084391824351615f;  // 1/sqrt(768)

  // Q fragments; B-operand layout == A-operand layout per-lane, so these
  // serve as B for St and could serve as A elsewhere.
  bf16x8 aq[2][2];
#pragma unroll
  for (int nt = 0; nt < 2; ++nt)
#pragma unroll
    for (int kc = 0; kc < 2; ++kc)
      aq[nt][kc] = *(const bf16x8*)(Kb + (size_t)(q0 + qw + nt * 16 + r16) * DH + kc * 32 + quad * 8);

  // mask folded into scale: masked row -> arg 0 -> p=1 (uniform softmax)
  float scm[2];
#pragma unroll
  for (int nt = 0; nt < 2; ++nt)
    scm[nt] = (mask[b * SEQ + q0 + qw + nt * 16 + r16] != 0) ? SCALE : 0.0f;

  floatx4 accO[2][4] = {};
  float psum[2] = {};

  auto stage = [&](int kt, int buf) {
    unsigned short* Ks  = smem + buf * 4096;
    unsigned short* KTs = smem + 8192 + buf * 4096;
#pragma unroll
    for (int i = 0; i < 2; ++i) {
      int c = tid + i * 256;
      int row = c >> 3, g = (c & 7) ^ (row & 7);
      GLOAD16(Kb + (size_t)(kt + row) * DH + g * 8,
              Ks + (size_t)(wbase + i * 256) * 8);
    }
#pragma unroll
    for (int i = 0; i < 2; ++i) {
      int c = tid + i * 256;
      int row = c >> 3, g = (c & 7) ^ (row & 7);
      GLOAD16(KbT + (size_t)row * SEQ + kt + g * 8,
              KTs + (size_t)(wbase + i * 256) * 8);
    }
  };

  stage(0, 0);
  int buf = 0;
  for (int it = 0; it < SEQ / 64; ++it) {
    __syncthreads();
    if (it + 1 < SEQ / 64) stage((it + 1) * 64, buf ^ 1);
    const unsigned short* Ks  = smem + buf * 4096;
    const unsigned short* KTs = smem + 8192 + buf * 4096;

    // St[key][q] = K Q^T ; A = K-frag (m=key), B = aq (n=q)
    floatx4 St[4][2] = {};
#pragma unroll
    for (int kt = 0; kt < 4; ++kt) {
      int rb = (kt * 16 + r16) * 64;
      bf16x8 k0 = *(const bf16x8*)&Ks[rb + ((quad) ^ rs) * 8];
      bf16x8 k1 = *(const bf16x8*)&Ks[rb + ((4 + quad) ^ rs) * 8];
#pragma unroll
      for (int nt = 0; nt < 2; ++nt) {
        St[kt][nt] = __builtin_amdgcn_mfma_f32_16x16x32_bf16(k0, aq[nt][0], St[kt][nt], 0, 0, 0);
        St[kt][nt] = __builtin_amdgcn_mfma_f32_16x16x32_bf16(k1, aq[nt][1], St[kt][nt], 0, 0, 0);
      }
    }

    // P: lane holds keys kt*16+quad*4+{0..3} for q = qw+nt*16+r16
    // -> exp, packed cvt, ONE b64 LDS write per (nt,kt)
#pragma unroll
    for (int nt = 0; nt < 2; ++nt) {
      float sc = scm[nt];
      int prow = (qw + nt * 16 + r16) * 68 + quad * 4;
#pragma unroll
      for (int kt = 0; kt < 4; ++kt) {
        float p0 = __expf(St[kt][nt][0] * sc);
        float p1 = __expf(St[kt][nt][1] * sc);
        float p2 = __expf(St[kt][nt][2] * sc);
        float p3 = __expf(St[kt][nt][3] * sc);
        psum[nt] += (p0 + p1) + (p2 + p3);
        __hip_bfloat162 lo = __float22bfloat162_rn(make_float2(p0, p1));
        __hip_bfloat162 hi = __float22bfloat162_rn(make_float2(p2, p3));
        unsigned u0, u1;
        __builtin_memcpy(&u0, &lo, 4);
        __builtin_memcpy(&u1, &hi, 4);
        *(uint2*)&Ps[prow + kt * 16] = make_uint2(u0, u1);
      }
    }

    // O += P V (same-wave LDS RAW on Ps; V^T tile from KTs)
    bf16x8 ap[2][2];
#pragma unroll
    for (int mi = 0; mi < 2; ++mi)
#pragma unroll
      for (int kc = 0; kc < 2; ++kc)
        ap[mi][kc] = *(const bf16x8*)&Ps[(qw + mi * 16 + r16) * 68 + kc * 32 + quad * 8];
#pragma unroll
    for (int ni = 0; ni < 4; ++ni) {
      int rb = (ni * 16 + r16) * 64;
      bf16x8 v0 = *(const bf16x8*)&KTs[rb + ((quad) ^ rs) * 8];
      bf16x8 v1 = *(const bf16x8*)&KTs[rb + ((4 + quad) ^ rs) * 8];
#pragma unroll
      for (int mi = 0; mi < 2; ++mi) {
        accO[mi][ni] = __builtin_amdgcn_mfma_f32_16x16x32_bf16(ap[mi][0], v0, accO[mi][ni], 0, 0, 0);
        accO[mi][ni] = __builtin_amdgcn_mfma_f32_16x16x32_bf16(ap[mi][1], v1, accO[mi][ni], 0, 0, 0);
      }
    }
    buf ^= 1;
  }

  // psum lives at q = qw+nt*16+r16 (quad-partial): reduce over quads, then
  // LDS hop to re-align with the O epilogue's q = quad*4+r layout.
#pragma unroll
  for (int nt = 0; nt < 2; ++nt) {
    float s = psum[nt];
    s += __shfl_xor(s, 16);
    s += __shfl_xor(s, 32);
    psum[nt] = s;
  }
  if (quad == 0) {
#pragma unroll
    for (int nt = 0; nt < 2; ++nt)
      rsum[qw + nt * 16 + r16] = psum[nt];
  }
  // same-wave DS in-order: reads below see the writes above (own q-range only)
  float rinv[2][4];
#pragma unroll
  for (int mi = 0; mi < 2; ++mi)
#pragma unroll
    for (int r = 0; r < 4; ++r)
      rinv[mi][r] = 1.0f / rsum[qw + mi * 16 + quad * 4 + r];

#pragma unroll
  for (int mi = 0; mi < 2; ++mi)
#pragma unroll
    for (int ni = 0; ni < 4; ++ni)
#pragma unroll
      for (int r = 0; r < 4; ++r) {
        int l = q0 + qw + mi * 16 + quad * 4 + r;
        int col = h * DH + ni * 16 + r16;
        wV[(size_t)(b * SEQ + l) * DIM + col] = f2bf(accO[mi][ni][r] * rinv[mi][r]);
      }
}

// ---------------- output projection: out = wV @ Wo^T + bo (fp32) -----------
__global__ __launch_bounds__(256) void proj_o_kernel(
    const unsigned short* __restrict__ wVb, const unsigned short* __restrict__ Wob,
    const float* __restrict__ bo, float* __restrict__ out)
{
  __shared__ __align__(16) unsigned short smem[24576];   // 48 KB
  const int tid = threadIdx.x;
  const int lane = tid & 63;
  const int w = tid >> 6;
  const int wr = w >> 1, wc = w & 1;
  const int quad = lane >> 4, r16 = lane & 15;
  const int rs = r16 & 7;
  const int m0 = blockIdx.x * 64, n0 = blockIdx.y * 128;
  const int wbase = (tid & ~63);

  floatx4 acc[2][4] = {};

  auto stage = [&](int kt, int buf) {
    unsigned short* As = smem + buf * 12288;
    unsigned short* Bs = As + 4096;
#pragma unroll
    for (int i = 0; i < 2; ++i) {
      int c = tid + i * 256;
      int row = c >> 3, g = (c & 7) ^ (row & 7);
      GLOAD16(wVb + (size_t)(m0 + row) * DIM + kt + g * 8,
              As + (size_t)(wbase + i * 256) * 8);
    }
#pragma unroll
    for (int i = 0; i < 4; ++i) {
      int c = tid + i * 256;
      int row = c >> 3, g = (c & 7) ^ (row & 7);
      GLOAD16(Wob + (size_t)(n0 + row) * DIM + kt + g * 8,
              Bs + (size_t)(wbase + i * 256) * 8);
    }
  };

  stage(0, 0);
  int buf = 0;
  for (int it = 0; it < 12; ++it) {
    __syncthreads();
    if (it + 1 < 12) stage((it + 1) * 64, buf ^ 1);
    const unsigned short* As = smem + buf * 12288;
    const unsigned short* Bs = As + 4096;
    bf16x8 af[2][2], bfm[4][2];
#pragma unroll
    for (int mi = 0; mi < 2; ++mi)
#pragma unroll
      for (int kc = 0; kc < 2; ++kc)
        af[mi][kc] = *(const bf16x8*)&As[(wr * 32 + mi * 16 + r16) * 64 + ((kc * 4 + quad) ^ rs) * 8];
#pragma unroll
    for (int ni = 0; ni < 4; ++ni)
#pragma unroll
      for (int kc = 0; kc < 2; ++kc)
        bfm[ni][kc] = *(const bf16x8*)&Bs[(wc * 64 + ni * 16 + r16) * 64 + ((kc * 4 + quad) ^ rs) * 8];
#pragma unroll
    for (int mi = 0; mi < 2; ++mi)
#pragma unroll
      for (int ni = 0; ni < 4; ++ni) {
        acc[mi][ni] = __builtin_amdgcn_mfma_f32_16x16x32_bf16(af[mi][0], bfm[ni][0], acc[mi][ni], 0, 0, 0);
        acc[mi][ni] = __builtin_amdgcn_mfma_f32_16x16x32_bf16(af[mi][1], bfm[ni][1], acc[mi][ni], 0, 0, 0);
      }
    buf ^= 1;
  }

#pragma unroll
  for (int mi = 0; mi < 2; ++mi)
#pragma unroll
    for (int ni = 0; ni < 4; ++ni) {
      int col = n0 + wc * 64 + ni * 16 + r16;
      float bias = bo[col];
#pragma unroll
      for (int r = 0; r < 4; ++r) {
        int row = m0 + wr * 32 + mi * 16 + quad * 4 + r;
        out[(size_t)row * DIM + col] = acc[mi][ni][r] + bias;
      }
    }
}

extern "C" void kernel_launch(void* const* d_in, const int* in_sizes, int n_in,
                              void* d_out, int out_size, void* d_ws, size_t ws_size,
                              hipStream_t stream) {
  // inputs: x, attention_mask, Wq, bq, Wk, bk, Wv, bv, Wo, bo  (Q dead; V==K)
  const float* x  = (const float*)d_in[0];
  const int* mask = (const int*)d_in[1];
  const float* Wk = (const float*)d_in[4];
  const float* bk = (const float*)d_in[5];
  const float* Wo = (const float*)d_in[8];
  const float* bo = (const float*)d_in[9];
  float* out = (float*)d_out;

  unsigned short* p = (unsigned short*)d_ws;
  unsigned short* xb   = p;  p += (size_t)8192 * 768;
  unsigned short* Wkb  = p;  p += (size_t)768 * 768;
  unsigned short* Wob  = p;  p += (size_t)768 * 768;
  unsigned short* Kbh  = p;  p += (size_t)NUM_B * NH * SEQ * DH;
  unsigned short* KbhT = p;  p += (size_t)NUM_B * NH * SEQ * DH;
  unsigned short* wVb  = p;  // [8192][768]

  convert_kernel<<<7296, 256, 0, stream>>>(x, Wk, Wo, xb, Wkb, Wob);
  proj_k_kernel<<<dim3(128, 6), 256, 0, stream>>>(xb, Wkb, bk, Kbh, KbhT);
  attn_kernel<<<dim3(8, NUM_B * NH), 256, 0, stream>>>(Kbh, KbhT, mask, wVb);
  proj_o_kernel<<<dim3(128, 6), 256, 0, stream>>>(wVb, Wob, bo, out);
}